// Round 1
// baseline (2629.456 us; speedup 1.0000x reference)
//
#include <hip/hip_runtime.h>
#include <cstdint>

#define HEADS 32
#define SEQ 1024
#define HD 128
#define DMODEL 4096
#define HB 102      // heavy budget = int(0.1*1024)
#define RB 102      // recent budget
#define KEEP 101    // HB-1 (top_k k)

typedef _Float16 half8_t __attribute__((ext_vector_type(8)));
typedef _Float16 half4_t __attribute__((ext_vector_type(4)));
typedef float f32x4 __attribute__((ext_vector_type(4)));

// ---------------------------------------------------------------------------
// GEMM: C = A * B^T  (A: [M x K] row-major, B: [N x K] row-major — torch
// Linear convention y = x W^T). SPLIT=true: fp16 hi/lo 3-MFMA fp32-precision
// emulation. OUTMODE 0: C[row*N+col]. OUTMODE 1: head-scatter to [h][s][hd].
// Tiles: 128x128 per workgroup (256 thr, 4 waves 2x2, each wave 64x64, 4x4
// tiles of 16x16x32 f16 MFMA), BK=32.
// ---------------------------------------------------------------------------
template<bool SPLIT, int OUTMODE>
__global__ __launch_bounds__(256)
void gemm_f16(const float* __restrict__ Ag, const float* __restrict__ Bg,
              float* __restrict__ Cg, int K, int N,
              long sA, long sB, long sC, float scale)
{
    constexpr int NSP = SPLIT ? 2 : 1;
    __shared__ __align__(16) _Float16 AH[NSP][128][40]; // 40-half row stride: 80B (16B mult, breaks pow2 banks)
    __shared__ __align__(16) _Float16 BH[NSP][128][40];

    const int b = blockIdx.z;
    const float* A = Ag + (long)b * sA;
    const float* Bm = Bg + (long)b * sB;
    float* C = Cg + (long)b * sC;

    const int m0 = blockIdx.y * 128, n0 = blockIdx.x * 128;
    const int tid = threadIdx.x;
    const int lane = tid & 63, wid = tid >> 6;
    const int wm = (wid & 1) * 64, wn = (wid >> 1) * 64;
    const int l16 = lane & 15, quad = lane >> 4;

    f32x4 zero4 = {0.f, 0.f, 0.f, 0.f};
    f32x4 acc[4][4];
    for (int i = 0; i < 4; ++i)
        for (int j = 0; j < 4; ++j) acc[i][j] = zero4;

    const int sr = tid >> 1;          // staging row 0..127
    const int sc = (tid & 1) * 16;    // staging col offset

    for (int k0 = 0; k0 < K; k0 += 32) {
        // ---- stage A,B tiles (fp32 -> f16 hi[/lo]) ----
        const float* srcA = A + (long)(m0 + sr) * K + k0 + sc;
        const float* srcB = Bm + (long)(n0 + sr) * K + k0 + sc;
#pragma unroll
        for (int i = 0; i < 4; ++i) {
            float4 v = ((const float4*)srcA)[i];
            _Float16 h0 = (_Float16)v.x, h1 = (_Float16)v.y,
                     h2 = (_Float16)v.z, h3 = (_Float16)v.w;
            *(half4_t*)&AH[0][sr][sc + 4*i] = (half4_t){h0, h1, h2, h3};
            if (SPLIT)
                *(half4_t*)&AH[NSP-1][sr][sc + 4*i] = (half4_t){
                    (_Float16)(v.x - (float)h0), (_Float16)(v.y - (float)h1),
                    (_Float16)(v.z - (float)h2), (_Float16)(v.w - (float)h3)};
            float4 w = ((const float4*)srcB)[i];
            _Float16 g0 = (_Float16)w.x, g1 = (_Float16)w.y,
                     g2 = (_Float16)w.z, g3 = (_Float16)w.w;
            *(half4_t*)&BH[0][sr][sc + 4*i] = (half4_t){g0, g1, g2, g3};
            if (SPLIT)
                *(half4_t*)&BH[NSP-1][sr][sc + 4*i] = (half4_t){
                    (_Float16)(w.x - (float)g0), (_Float16)(w.y - (float)g1),
                    (_Float16)(w.z - (float)g2), (_Float16)(w.w - (float)g3)};
        }
        __syncthreads();

        half8_t ah[4], bh[4], al[4], bl[4];
#pragma unroll
        for (int i = 0; i < 4; ++i) {
            ah[i] = *(const half8_t*)&AH[0][wm + i*16 + l16][quad * 8];
            bh[i] = *(const half8_t*)&BH[0][wn + i*16 + l16][quad * 8];
            if (SPLIT) {
                al[i] = *(const half8_t*)&AH[NSP-1][wm + i*16 + l16][quad * 8];
                bl[i] = *(const half8_t*)&BH[NSP-1][wn + i*16 + l16][quad * 8];
            }
        }
#pragma unroll
        for (int mt = 0; mt < 4; ++mt)
#pragma unroll
            for (int nt = 0; nt < 4; ++nt) {
                acc[mt][nt] = __builtin_amdgcn_mfma_f32_16x16x32_f16(ah[mt], bh[nt], acc[mt][nt], 0, 0, 0);
                if (SPLIT) {
                    acc[mt][nt] = __builtin_amdgcn_mfma_f32_16x16x32_f16(ah[mt], bl[nt], acc[mt][nt], 0, 0, 0);
                    acc[mt][nt] = __builtin_amdgcn_mfma_f32_16x16x32_f16(al[mt], bh[nt], acc[mt][nt], 0, 0, 0);
                }
            }
        __syncthreads();
    }

    // ---- epilogue: C/D layout col=lane&15, row=quad*4+reg ----
#pragma unroll
    for (int mt = 0; mt < 4; ++mt)
#pragma unroll
        for (int nt = 0; nt < 4; ++nt)
#pragma unroll
            for (int r = 0; r < 4; ++r) {
                int row = m0 + wm + mt*16 + quad*4 + r;
                int col = n0 + wn + nt*16 + l16;
                float v = acc[mt][nt][r] * scale;
                if (OUTMODE == 0)
                    C[(long)row * N + col] = v;
                else // head scatter: col -> (head, hd); out [h][s][hd]
                    C[(long)(col >> 7) * (SEQ * HD) + (long)row * HD + (col & 127)] = v;
            }
}

// ---------------------------------------------------------------------------
// RoPE, in place on Q and K stored [h][s][hd].
// ---------------------------------------------------------------------------
__global__ __launch_bounds__(256)
void rope_kernel(float* __restrict__ Q, float* __restrict__ Kr)
{
    int idx = blockIdx.x * 256 + threadIdx.x;   // HEADS*SEQ*64
    if (idx >= HEADS * SEQ * 64) return;
    int d = idx & 63;
    int s = (idx >> 6) & (SEQ - 1);
    int h = idx >> 16;
    long base = ((long)h * SEQ + s) * HD;
    float inv = 1.0f / powf(10000.0f, (float)(2 * d) / 128.0f);  // matches jnp fp32 formula
    float ang = (float)s * inv;
    float c = cosf(ang), sn = sinf(ang);
    float q1 = Q[base + d], q2 = Q[base + d + 64];
    Q[base + d]      = q1 * c - q2 * sn;
    Q[base + d + 64] = q2 * c + q1 * sn;
    float k1 = Kr[base + d], k2 = Kr[base + d + 64];
    Kr[base + d]      = k1 * c - k2 * sn;
    Kr[base + d + 64] = k2 * c + k1 * sn;
}

// ---------------------------------------------------------------------------
// Row softmax stats. phase 1: causal only (for the H2O scan probabilities).
// phase 2: final mask = causal & (recent | heavy-bitmap) (rows<HB: causal).
// One wave per row.
// ---------------------------------------------------------------------------
__global__ __launch_bounds__(64)
void stats_kernel(const float* __restrict__ S, const uint32_t* __restrict__ mb,
                  float* __restrict__ mx_o, float* __restrict__ rd_o, int phase)
{
    int row = blockIdx.x;            // h*SEQ + t
    int t = row & (SEQ - 1);
    const float* Sr = S + (long)row * SEQ;
    const uint32_t* mrow = mb + (long)row * 32;
    int tid = threadIdx.x;
    bool use_mask = (phase == 2) && (t >= HB);

    float lm = -3.4e38f;
    for (int j = tid; j <= t; j += 64) {
        bool ok = !use_mask || (j >= t - RB) || ((mrow[j >> 5] >> (j & 31)) & 1);
        if (ok) lm = fmaxf(lm, Sr[j]);
    }
#pragma unroll
    for (int off = 32; off; off >>= 1) lm = fmaxf(lm, __shfl_xor(lm, off));

    float ls = 0.f;
    for (int j = tid; j <= t; j += 64) {
        bool ok = !use_mask || (j >= t - RB) || ((mrow[j >> 5] >> (j & 31)) & 1);
        if (ok) ls += expf(Sr[j] - lm);
    }
#pragma unroll
    for (int off = 32; off; off >>= 1) ls += __shfl_xor(ls, off);

    if (tid == 0) { mx_o[row] = lm; rd_o[row] = 1.0f / ls; }
}

// ---------------------------------------------------------------------------
// H2O sequential scan. One wave per head; 128 slots (2 per lane) hold the
// active columns' accumulated scores in registers. Each step extracts the
// (P-101) smallest by 64-bit key (acc_bits<<10 | (1023-col): exact top_k tie
// semantics — equal values drop higher col first), kills unprotected ones,
// claims a dead slot for col t, adds row-t probs, writes the row's bitmap.
// S row t+1 is prefetched into the other LDS buffer during step t.
// ---------------------------------------------------------------------------
__global__ __launch_bounds__(64)
void scan_kernel(const float* __restrict__ S, const float* __restrict__ mx1,
                 const float* __restrict__ rd1, uint32_t* __restrict__ mb)
{
    const int h = blockIdx.x, tid = threadIdx.x;
    const float* Sh = S + (long)h * SEQ * SEQ;
    const float* mx = mx1 + h * SEQ;
    const float* rd = rd1 + h * SEQ;
    __shared__ float srow[2][SEQ];
    __shared__ uint32_t bm[32];

    int col0 = tid, col1 = 64 + tid;
    bool al0 = true, al1 = (col1 < HB);
    float ac0 = 0.f, ac1 = 0.f;

    // acc0[j] = sum_{t=j..HB-1} softmax_row_t[j]
    for (int t = 0; t < HB; ++t) {
        float m = mx[t], r = rd[t];
        if (t >= col0) ac0 += expf(Sh[(long)t * SEQ + col0] - m) * r;
        if (al1 && t >= col1) ac1 += expf(Sh[(long)t * SEQ + col1] - m) * r;
    }

    { // preload row HB into buffer 0
        const float4* src = (const float4*)(Sh + (long)HB * SEQ);
        float4* dst = (float4*)srow[0];
#pragma unroll
        for (int i = 0; i < 4; ++i) dst[tid * 4 + i] = src[tid * 4 + i];
    }
    __syncthreads();

    int P = HB;
    for (int t = HB; t < SEQ; ++t) {
        const int buf = t & 1;
        float4 pre[4];
        if (t < SEQ - 1) {
            const float4* src = (const float4*)(Sh + (long)(t + 1) * SEQ);
#pragma unroll
            for (int i = 0; i < 4; ++i) pre[i] = src[tid * 4 + i];
        }

        // ---- extract (P-101) smallest of acc (top_k semantics) ----
        unsigned long long k0 = al0 ? ((((unsigned long long)__float_as_uint(ac0)) << 10) | (unsigned)(1023 - col0)) : ~0ull;
        unsigned long long k1 = al1 ? ((((unsigned long long)__float_as_uint(ac1)) << 10) | (unsigned)(1023 - col1)) : ~0ull;
        int nex = P - KEEP;
        for (int e = 0; e < nex; ++e) {
            unsigned long long m = k0 < k1 ? k0 : k1;
#pragma unroll
            for (int off = 32; off; off >>= 1) {
                unsigned long long o = __shfl_xor(m, off);
                if (o < m) m = o;
            }
            if (k0 == m)      { k0 = ~0ull; if (col0 >= 4) al0 = false; }
            else if (k1 == m) { k1 = ~0ull; if (col1 >= 4) al1 = false; }
        }

        // ---- claim one dead slot for col t ----
        unsigned long long d0 = __ballot(!al0);
        if (d0) {
            if (tid == __ffsll(d0) - 1) { col0 = t; ac0 = 0.f; al0 = true; }
        } else {
            unsigned long long d1 = __ballot(!al1);
            if (tid == __ffsll(d1) - 1) { col1 = t; ac1 = 0.f; al1 = true; }
        }
        P = __popcll(__ballot(al0)) + __popcll(__ballot(al1));

        // ---- accumulate probs of row t at surviving columns ----
        float m_ = mx[t], r_ = rd[t];
        if (al0) ac0 += expf(srow[buf][col0] - m_) * r_;
        if (al1) ac1 += expf(srow[buf][col1] - m_) * r_;

        // ---- emit bitmap for row t ----
        if (tid < 32) bm[tid] = 0;
        if (al0) atomicOr(&bm[col0 >> 5], 1u << (col0 & 31));
        if (al1) atomicOr(&bm[col1 >> 5], 1u << (col1 & 31));
        if (tid < 32) mb[((long)h * SEQ + t) * 32 + tid] = bm[tid];

        // ---- commit prefetched row ----
        if (t < SEQ - 1) {
            float4* dst = (float4*)srow[buf ^ 1];
#pragma unroll
            for (int i = 0; i < 4; ++i) dst[tid * 4 + i] = pre[i];
        }
        __syncthreads();
    }
}

// ---------------------------------------------------------------------------
// PV: ctx[s][h][hd] = sum_j P[h][s][j] * V[h][j][hd], P built on the fly from
// S + mask + stats2, f16 MFMA. WG = 64 q-rows x 128 hd, j-tiles of 64.
// ---------------------------------------------------------------------------
__global__ __launch_bounds__(256)
void pv_kernel(const float* __restrict__ S, const float* __restrict__ V,
               const uint32_t* __restrict__ mb, const float* __restrict__ mx2,
               const float* __restrict__ rd2, float* __restrict__ ctx)
{
    const int rb = blockIdx.x, h = blockIdx.y;
    const int tid = threadIdx.x, lane = tid & 63, wid = tid >> 6;
    const int wm = (wid & 1) * 32, wn = (wid >> 1) * 64;
    const int l16 = lane & 15, quad = lane >> 4;
    __shared__ __align__(16) _Float16 PT[64][72];
    __shared__ __align__(16) _Float16 VT[128][72];

    const int m0 = rb * 64;
    f32x4 zero4 = {0.f, 0.f, 0.f, 0.f};
    f32x4 acc[2][4];
    for (int i = 0; i < 2; ++i)
        for (int j = 0; j < 4; ++j) acc[i][j] = zero4;

    const float* Sh = S + ((long)h * SEQ + m0) * SEQ;
    const float* Vh = V + (long)h * SEQ * HD;

    const int pr = tid >> 2, pc = (tid & 3) * 16;  // P staging: row, col base
    const int trow = m0 + pr;
    const float pmx = mx2[h * SEQ + trow], prd = rd2[h * SEQ + trow];
    const uint32_t* mrow = mb + ((long)h * SEQ + trow) * 32;
    const bool use_mask = (trow >= HB);

    for (int jt = 0; jt <= rb; ++jt) {
        int j0 = jt * 64;
        // stage P tile (probabilities) as f16, A-operand layout [m][k]
#pragma unroll
        for (int i = 0; i < 4; ++i) {
            float4 v = *(const float4*)(Sh + (long)pr * SEQ + j0 + pc + i * 4);
#pragma unroll
            for (int u = 0; u < 4; ++u) {
                int j = j0 + pc + i * 4 + u;
                float s = (u == 0) ? v.x : (u == 1) ? v.y : (u == 2) ? v.z : v.w;
                bool ok = (j <= trow) &&
                          (!use_mask || j >= trow - RB || ((mrow[j >> 5] >> (j & 31)) & 1));
                float p = ok ? expf(s - pmx) * prd : 0.f;
                PT[pr][pc + i * 4 + u] = (_Float16)p;
            }
        }
        // stage V tile transposed: VT[hd][j], B-operand layout
#pragma unroll
        for (int i = 0; i < 8; ++i) {
            int flat = i * 256 + tid;
            int j = flat >> 5, c4 = (flat & 31) * 4;
            float4 v = *(const float4*)(Vh + (long)(j0 + j) * HD + c4);
            VT[c4 + 0][j] = (_Float16)v.x;
            VT[c4 + 1][j] = (_Float16)v.y;
            VT[c4 + 2][j] = (_Float16)v.z;
            VT[c4 + 3][j] = (_Float16)v.w;
        }
        __syncthreads();
#pragma unroll
        for (int ks = 0; ks < 2; ++ks) {
            half8_t a[2], bf[4];
#pragma unroll
            for (int i = 0; i < 2; ++i)
                a[i] = *(const half8_t*)&PT[wm + i * 16 + l16][ks * 32 + quad * 8];
#pragma unroll
            for (int i = 0; i < 4; ++i)
                bf[i] = *(const half8_t*)&VT[wn + i * 16 + l16][ks * 32 + quad * 8];
#pragma unroll
            for (int mt = 0; mt < 2; ++mt)
#pragma unroll
                for (int nt = 0; nt < 4; ++nt)
                    acc[mt][nt] = __builtin_amdgcn_mfma_f32_16x16x32_f16(a[mt], bf[nt], acc[mt][nt], 0, 0, 0);
        }
        __syncthreads();
    }
    // write ctx [s][h*HD+hd]
#pragma unroll
    for (int mt = 0; mt < 2; ++mt)
#pragma unroll
        for (int nt = 0; nt < 4; ++nt)
#pragma unroll
            for (int r = 0; r < 4; ++r) {
                int s_ = m0 + wm + mt * 16 + quad * 4 + r;
                int hd = wn + nt * 16 + l16;
                ctx[(long)s_ * DMODEL + h * HD + hd] = acc[mt][nt][r];
            }
}

// ---------------------------------------------------------------------------
extern "C" void kernel_launch(void* const* d_in, const int* in_sizes, int n_in,
                              void* d_out, int out_size, void* d_ws, size_t ws_size,
                              hipStream_t stream)
{
    const float* hs = (const float*)d_in[0];
    // d_in[1] = attention_mask: structure known (causal), not needed
    const float* Wq = (const float*)d_in[2];
    const float* Wk = (const float*)d_in[3];
    const float* Wv = (const float*)d_in[4];
    const float* Wo = (const float*)d_in[5];
    float* out = (float*)d_out;

    char* w = (char*)d_ws;
    float* Qr  = (float*)w;  w += (long)HEADS * SEQ * HD * 4;   // 16MB
    float* Kr  = (float*)w;  w += (long)HEADS * SEQ * HD * 4;   // 16MB
    float* V   = (float*)w;  w += (long)HEADS * SEQ * HD * 4;   // 16MB
    float* ctx = (float*)w;  w += (long)SEQ * DMODEL * 4;       // 16MB
    float* mx1 = (float*)w;  w += (long)HEADS * SEQ * 4;
    float* rd1 = (float*)w;  w += (long)HEADS * SEQ * 4;
    float* mx2 = (float*)w;  w += (long)HEADS * SEQ * 4;
    float* rd2 = (float*)w;  w += (long)HEADS * SEQ * 4;
    uint32_t* mb = (uint32_t*)w; w += (long)HEADS * SEQ * 32 * 4; // 4MB
    float* S   = (float*)w;  w += (long)HEADS * SEQ * SEQ * 4;  // 134MB

    const float inv_sqrt_hd = 0.088388347648318447f; // 1/sqrt(128)

    dim3 gproj(DMODEL / 128, SEQ / 128, 1);
    // Q,K: fp32-precision split GEMM (mask decisions depend on them)
    gemm_f16<true, 1><<<gproj, 256, 0, stream>>>(hs, Wq, Qr, DMODEL, DMODEL, 0, 0, 0, 1.f);
    gemm_f16<true, 1><<<gproj, 256, 0, stream>>>(hs, Wk, Kr, DMODEL, DMODEL, 0, 0, 0, 1.f);
    // V: plain f16 MFMA
    gemm_f16<false, 1><<<gproj, 256, 0, stream>>>(hs, Wv, V, DMODEL, DMODEL, 0, 0, 0, 1.f);

    rope_kernel<<<(HEADS * SEQ * 64) / 256, 256, 0, stream>>>(Qr, Kr);

    // S = Q K^T / sqrt(hd), split precision, batched over heads
    dim3 gsc(SEQ / 128, SEQ / 128, HEADS);
    gemm_f16<true, 0><<<gsc, 256, 0, stream>>>(Qr, Kr, S, HD, SEQ,
        (long)SEQ * HD, (long)SEQ * HD, (long)SEQ * SEQ, inv_sqrt_hd);

    stats_kernel<<<HEADS * SEQ, 64, 0, stream>>>(S, mb, mx1, rd1, 1);
    scan_kernel<<<HEADS, 64, 0, stream>>>(S, mx1, rd1, mb);
    stats_kernel<<<HEADS * SEQ, 64, 0, stream>>>(S, mb, mx2, rd2, 2);
    pv_kernel<<<dim3(SEQ / 64, HEADS), 256, 0, stream>>>(S, V, mb, mx2, rd2, ctx);

    // out = ctx Wo^T
    gemm_f16<false, 0><<<gproj, 256, 0, stream>>>(ctx, Wo, out, DMODEL, DMODEL, 0, 0, 0, 1.f);
}

// Round 2
// 1929.572 us; speedup vs baseline: 1.3627x; 1.3627x over previous
//
#include <hip/hip_runtime.h>
#include <cstdint>

#define HEADS 32
#define SEQ 1024
#define HD 128
#define DMODEL 4096
#define HB 102      // heavy budget = int(0.1*1024)
#define RB 102      // recent budget
#define KEEP 101    // HB-1 (top_k k)

typedef _Float16 half8_t __attribute__((ext_vector_type(8)));
typedef _Float16 half4_t __attribute__((ext_vector_type(4)));
typedef float f32x4 __attribute__((ext_vector_type(4)));

// ---------------------------------------------------------------------------
// GEMM: C = A * B^T  (A: [M x K] row-major, B: [N x K] row-major — torch
// Linear convention y = x W^T). SPLIT=true: fp16 hi/lo 3-MFMA fp32-precision
// emulation. OUTMODE 0: C[row*N+col]. OUTMODE 1: head-scatter to [h][s][hd].
// Tiles: 128x128 per workgroup (256 thr, 4 waves 2x2, each wave 64x64, 4x4
// tiles of 16x16x32 f16 MFMA), BK=32.
// ---------------------------------------------------------------------------
template<bool SPLIT, int OUTMODE>
__global__ __launch_bounds__(256)
void gemm_f16(const float* __restrict__ Ag, const float* __restrict__ Bg,
              float* __restrict__ Cg, int K, int N,
              long sA, long sB, long sC, float scale)
{
    constexpr int NSP = SPLIT ? 2 : 1;
    __shared__ __align__(16) _Float16 AH[NSP][128][40]; // 40-half row stride: 80B (16B mult, breaks pow2 banks)
    __shared__ __align__(16) _Float16 BH[NSP][128][40];

    const int b = blockIdx.z;
    const float* A = Ag + (long)b * sA;
    const float* Bm = Bg + (long)b * sB;
    float* C = Cg + (long)b * sC;

    const int m0 = blockIdx.y * 128, n0 = blockIdx.x * 128;
    const int tid = threadIdx.x;
    const int lane = tid & 63, wid = tid >> 6;
    const int wm = (wid & 1) * 64, wn = (wid >> 1) * 64;
    const int l16 = lane & 15, quad = lane >> 4;

    f32x4 zero4 = {0.f, 0.f, 0.f, 0.f};
    f32x4 acc[4][4];
    for (int i = 0; i < 4; ++i)
        for (int j = 0; j < 4; ++j) acc[i][j] = zero4;

    const int sr = tid >> 1;          // staging row 0..127
    const int sc = (tid & 1) * 16;    // staging col offset

    for (int k0 = 0; k0 < K; k0 += 32) {
        // ---- stage A,B tiles (fp32 -> f16 hi[/lo]) ----
        const float* srcA = A + (long)(m0 + sr) * K + k0 + sc;
        const float* srcB = Bm + (long)(n0 + sr) * K + k0 + sc;
#pragma unroll
        for (int i = 0; i < 4; ++i) {
            float4 v = ((const float4*)srcA)[i];
            _Float16 h0 = (_Float16)v.x, h1 = (_Float16)v.y,
                     h2 = (_Float16)v.z, h3 = (_Float16)v.w;
            *(half4_t*)&AH[0][sr][sc + 4*i] = (half4_t){h0, h1, h2, h3};
            if (SPLIT)
                *(half4_t*)&AH[NSP-1][sr][sc + 4*i] = (half4_t){
                    (_Float16)(v.x - (float)h0), (_Float16)(v.y - (float)h1),
                    (_Float16)(v.z - (float)h2), (_Float16)(v.w - (float)h3)};
            float4 w = ((const float4*)srcB)[i];
            _Float16 g0 = (_Float16)w.x, g1 = (_Float16)w.y,
                     g2 = (_Float16)w.z, g3 = (_Float16)w.w;
            *(half4_t*)&BH[0][sr][sc + 4*i] = (half4_t){g0, g1, g2, g3};
            if (SPLIT)
                *(half4_t*)&BH[NSP-1][sr][sc + 4*i] = (half4_t){
                    (_Float16)(w.x - (float)g0), (_Float16)(w.y - (float)g1),
                    (_Float16)(w.z - (float)g2), (_Float16)(w.w - (float)g3)};
        }
        __syncthreads();

        half8_t ah[4], bh[4], al[4], bl[4];
#pragma unroll
        for (int i = 0; i < 4; ++i) {
            ah[i] = *(const half8_t*)&AH[0][wm + i*16 + l16][quad * 8];
            bh[i] = *(const half8_t*)&BH[0][wn + i*16 + l16][quad * 8];
            if (SPLIT) {
                al[i] = *(const half8_t*)&AH[NSP-1][wm + i*16 + l16][quad * 8];
                bl[i] = *(const half8_t*)&BH[NSP-1][wn + i*16 + l16][quad * 8];
            }
        }
#pragma unroll
        for (int mt = 0; mt < 4; ++mt)
#pragma unroll
            for (int nt = 0; nt < 4; ++nt) {
                acc[mt][nt] = __builtin_amdgcn_mfma_f32_16x16x32_f16(ah[mt], bh[nt], acc[mt][nt], 0, 0, 0);
                if (SPLIT) {
                    acc[mt][nt] = __builtin_amdgcn_mfma_f32_16x16x32_f16(ah[mt], bl[nt], acc[mt][nt], 0, 0, 0);
                    acc[mt][nt] = __builtin_amdgcn_mfma_f32_16x16x32_f16(al[mt], bh[nt], acc[mt][nt], 0, 0, 0);
                }
            }
        __syncthreads();
    }

    // ---- epilogue: C/D layout col=lane&15, row=quad*4+reg ----
#pragma unroll
    for (int mt = 0; mt < 4; ++mt)
#pragma unroll
        for (int nt = 0; nt < 4; ++nt)
#pragma unroll
            for (int r = 0; r < 4; ++r) {
                int row = m0 + wm + mt*16 + quad*4 + r;
                int col = n0 + wn + nt*16 + l16;
                float v = acc[mt][nt][r] * scale;
                if (OUTMODE == 0)
                    C[(long)row * N + col] = v;
                else // head scatter: col -> (head, hd); out [h][s][hd]
                    C[(long)(col >> 7) * (SEQ * HD) + (long)row * HD + (col & 127)] = v;
            }
}

// ---------------------------------------------------------------------------
// RoPE, in place on Q and K stored [h][s][hd].
// ---------------------------------------------------------------------------
__global__ __launch_bounds__(256)
void rope_kernel(float* __restrict__ Q, float* __restrict__ Kr)
{
    int idx = blockIdx.x * 256 + threadIdx.x;   // HEADS*SEQ*64
    if (idx >= HEADS * SEQ * 64) return;
    int d = idx & 63;
    int s = (idx >> 6) & (SEQ - 1);
    int h = idx >> 16;
    long base = ((long)h * SEQ + s) * HD;
    float inv = 1.0f / powf(10000.0f, (float)(2 * d) / 128.0f);  // matches jnp fp32 formula
    float ang = (float)s * inv;
    float c = cosf(ang), sn = sinf(ang);
    float q1 = Q[base + d], q2 = Q[base + d + 64];
    Q[base + d]      = q1 * c - q2 * sn;
    Q[base + d + 64] = q2 * c + q1 * sn;
    float k1 = Kr[base + d], k2 = Kr[base + d + 64];
    Kr[base + d]      = k1 * c - k2 * sn;
    Kr[base + d + 64] = k2 * c + k1 * sn;
}

// ---------------------------------------------------------------------------
// Row softmax stats. phase 1: causal only (for the H2O scan probabilities).
// phase 2: final mask = causal & (recent | heavy-bitmap) (rows<HB: causal).
// One wave per row.
// ---------------------------------------------------------------------------
__global__ __launch_bounds__(64)
void stats_kernel(const float* __restrict__ S, const uint32_t* __restrict__ mb,
                  float* __restrict__ mx_o, float* __restrict__ rd_o, int phase)
{
    int row = blockIdx.x;            // h*SEQ + t
    int t = row & (SEQ - 1);
    const float* Sr = S + (long)row * SEQ;
    const uint32_t* mrow = mb + (long)row * 32;
    int tid = threadIdx.x;
    bool use_mask = (phase == 2) && (t >= HB);

    float lm = -3.4e38f;
    for (int j = tid; j <= t; j += 64) {
        bool ok = !use_mask || (j >= t - RB) || ((mrow[j >> 5] >> (j & 31)) & 1);
        if (ok) lm = fmaxf(lm, Sr[j]);
    }
#pragma unroll
    for (int off = 32; off; off >>= 1) lm = fmaxf(lm, __shfl_xor(lm, off));

    float ls = 0.f;
    for (int j = tid; j <= t; j += 64) {
        bool ok = !use_mask || (j >= t - RB) || ((mrow[j >> 5] >> (j & 31)) & 1);
        if (ok) ls += expf(Sr[j] - lm);
    }
#pragma unroll
    for (int off = 32; off; off >>= 1) ls += __shfl_xor(ls, off);

    if (tid == 0) { mx_o[row] = lm; rd_o[row] = 1.0f / ls; }
}

// ---------------------------------------------------------------------------
// Wave64 unsigned-min reduction via DPP (VALU latency, not LDS latency).
// Canonical GCN sequence; result valid in lane 63, broadcast via readlane.
// ---------------------------------------------------------------------------
__device__ __forceinline__ uint32_t wave_umin_bcast(uint32_t v)
{
    uint32_t t;
    t = (uint32_t)__builtin_amdgcn_update_dpp((int)v, (int)v, 0x111, 0xf, 0xf, false); v = t < v ? t : v; // row_shr:1
    t = (uint32_t)__builtin_amdgcn_update_dpp((int)v, (int)v, 0x112, 0xf, 0xf, false); v = t < v ? t : v; // row_shr:2
    t = (uint32_t)__builtin_amdgcn_update_dpp((int)v, (int)v, 0x114, 0xf, 0xe, false); v = t < v ? t : v; // row_shr:4
    t = (uint32_t)__builtin_amdgcn_update_dpp((int)v, (int)v, 0x118, 0xf, 0xc, false); v = t < v ? t : v; // row_shr:8
    t = (uint32_t)__builtin_amdgcn_update_dpp((int)v, (int)v, 0x142, 0xa, 0xf, false); v = t < v ? t : v; // row_bcast:15
    t = (uint32_t)__builtin_amdgcn_update_dpp((int)v, (int)v, 0x143, 0xc, 0xf, false); v = t < v ? t : v; // row_bcast:31
    return (uint32_t)__builtin_amdgcn_readlane((int)v, 63);
}

// ---------------------------------------------------------------------------
// H2O sequential scan. One wave per head; 128 slots (2 per lane) hold the
// active columns' accumulated scores in registers. Per step:
//   - DPP umin over acc bits (acc>=0 so IEEE bits order as uint) finds the
//     victim; exact ties (value-equal) resolved on a rare path by max-col
//     (matches jax top_k "lower index kept first" semantics exactly).
//   - one dead slot claims col t
//   - probs of row t accumulate from per-lane global loads issued one step
//     ahead (cols only change via the claim, covered by a broadcast S[t][t]).
// No LDS except the 32-word bitmap. No __syncthreads (single wave).
// ---------------------------------------------------------------------------
__global__ __launch_bounds__(64)
void scan_kernel(const float* __restrict__ S, const float* __restrict__ mx1,
                 const float* __restrict__ rd1, uint32_t* __restrict__ mb)
{
    const int h = blockIdx.x, tid = threadIdx.x;
    const float* Sh = S + (long)h * SEQ * SEQ;
    const float* mx = mx1 + h * SEQ;
    const float* rd = rd1 + h * SEQ;
    __shared__ uint32_t bm[32];

    int col0 = tid, col1 = 64 + tid;
    bool al0 = true, al1 = (col1 < HB);
    float ac0 = 0.f, ac1 = 0.f;

    // acc0[j] = sum_{t=j..HB-1} softmax_row_t[j]  (coalesced: col = lane)
    for (int t = 0; t < HB; ++t) {
        float m = mx[t], r = rd[t];
        if (t >= col0) ac0 += __expf(Sh[(long)t * SEQ + col0] - m) * r;
        if (al1 && t >= col1) ac1 += __expf(Sh[(long)t * SEQ + col1] - m) * r;
    }

    // preload row HB values at current cols
    float x0 = Sh[(long)HB * SEQ + col0];
    float x1 = Sh[(long)HB * SEQ + col1];
    float xt = Sh[(long)HB * SEQ + HB];

    int P = HB;
    for (int t = HB; t < SEQ; ++t) {
        // ---- keys: acc bits (>=0 so uint order == float order); dead = max ----
        uint32_t k0 = al0 ? __float_as_uint(ac0) : 0xFFFFFFFFu;
        uint32_t k1 = al1 ? __float_as_uint(ac1) : 0xFFFFFFFFu;

        // ---- extract (P-101) smallest (protected cols 0-3 stay alive) ----
        int nex = P - KEEP;
        for (int e = 0; e < nex; ++e) {
            uint32_t m = wave_umin_bcast(k0 < k1 ? k0 : k1);
            bool hit0 = (k0 == m), hit1 = (k1 == m);
            unsigned long long b0 = __ballot(hit0), b1 = __ballot(hit1);
            if (__popcll(b0) + __popcll(b1) > 1) {
                // exact-tie path (rare): drop the LARGEST col among candidates
                int c = hit0 ? col0 : -1;
                int c2 = hit1 ? col1 : -1;
                c = c > c2 ? c : c2;
#pragma unroll
                for (int off = 32; off; off >>= 1) {
                    int o = __shfl_xor(c, off);
                    c = o > c ? o : c;
                }
                hit0 = hit0 && (col0 == c);
                hit1 = hit1 && (col1 == c);
            }
            if (hit0)      { k0 = 0xFFFFFFFFu; if (col0 >= 4) al0 = false; }
            else if (hit1) { k1 = 0xFFFFFFFFu; if (col1 >= 4) al1 = false; }
        }

        // ---- claim one dead slot for col t ----
        bool claimed0 = false, claimed1 = false;
        unsigned long long d0 = __ballot(!al0);
        if (d0) {
            claimed0 = (tid == __ffsll(d0) - 1);
        } else {
            unsigned long long d1 = __ballot(!al1);
            claimed1 = (tid == __ffsll(d1) - 1);
        }
        if (claimed0) { col0 = t; ac0 = 0.f; al0 = true; }
        if (claimed1) { col1 = t; ac1 = 0.f; al1 = true; }
        P = __popcll(__ballot(al0)) + __popcll(__ballot(al1));

        // ---- issue loads for row t+1 at (post-claim) cols ----
        float nx0 = 0.f, nx1 = 0.f, nxt = 0.f;
        if (t + 1 < SEQ) {
            const float* Sn = Sh + (long)(t + 1) * SEQ;
            nx0 = Sn[col0]; nx1 = Sn[col1]; nxt = Sn[t + 1];
        }

        // ---- accumulate probs of row t at surviving columns ----
        float sm = mx[t], sr = rd[t];
        if (al0) ac0 += __expf((claimed0 ? xt : x0) - sm) * sr;
        if (al1) ac1 += __expf((claimed1 ? xt : x1) - sm) * sr;
        x0 = nx0; x1 = nx1; xt = nxt;

        // ---- emit bitmap for row t (in-order DS pipe, single wave) ----
        if (tid < 32) bm[tid] = 0;
        if (al0) atomicOr(&bm[col0 >> 5], 1u << (col0 & 31));
        if (al1) atomicOr(&bm[col1 >> 5], 1u << (col1 & 31));
        if (tid < 32) mb[((long)h * SEQ + t) * 32 + tid] = bm[tid];
    }
}

// ---------------------------------------------------------------------------
// PV: ctx[s][h][hd] = sum_j P[h][s][j] * V[h][j][hd], P built on the fly from
// S + mask + stats2, f16 MFMA. WG = 64 q-rows x 128 hd, j-tiles of 64.
// ---------------------------------------------------------------------------
__global__ __launch_bounds__(256)
void pv_kernel(const float* __restrict__ S, const float* __restrict__ V,
               const uint32_t* __restrict__ mb, const float* __restrict__ mx2,
               const float* __restrict__ rd2, float* __restrict__ ctx)
{
    const int rb = blockIdx.x, h = blockIdx.y;
    const int tid = threadIdx.x, lane = tid & 63, wid = tid >> 6;
    const int wm = (wid & 1) * 32, wn = (wid >> 1) * 64;
    const int l16 = lane & 15, quad = lane >> 4;
    __shared__ __align__(16) _Float16 PT[64][72];
    __shared__ __align__(16) _Float16 VT[128][72];

    const int m0 = rb * 64;
    f32x4 zero4 = {0.f, 0.f, 0.f, 0.f};
    f32x4 acc[2][4];
    for (int i = 0; i < 2; ++i)
        for (int j = 0; j < 4; ++j) acc[i][j] = zero4;

    const float* Sh = S + ((long)h * SEQ + m0) * SEQ;
    const float* Vh = V + (long)h * SEQ * HD;

    const int pr = tid >> 2, pc = (tid & 3) * 16;  // P staging: row, col base
    const int trow = m0 + pr;
    const float pmx = mx2[h * SEQ + trow], prd = rd2[h * SEQ + trow];
    const uint32_t* mrow = mb + ((long)h * SEQ + trow) * 32;
    const bool use_mask = (trow >= HB);

    for (int jt = 0; jt <= rb; ++jt) {
        int j0 = jt * 64;
        // stage P tile (probabilities) as f16, A-operand layout [m][k]
#pragma unroll
        for (int i = 0; i < 4; ++i) {
            float4 v = *(const float4*)(Sh + (long)pr * SEQ + j0 + pc + i * 4);
#pragma unroll
            for (int u = 0; u < 4; ++u) {
                int j = j0 + pc + i * 4 + u;
                float s = (u == 0) ? v.x : (u == 1) ? v.y : (u == 2) ? v.z : v.w;
                bool ok = (j <= trow) &&
                          (!use_mask || j >= trow - RB || ((mrow[j >> 5] >> (j & 31)) & 1));
                float p = ok ? expf(s - pmx) * prd : 0.f;
                PT[pr][pc + i * 4 + u] = (_Float16)p;
            }
        }
        // stage V tile transposed: VT[hd][j], B-operand layout
#pragma unroll
        for (int i = 0; i < 8; ++i) {
            int flat = i * 256 + tid;
            int j = flat >> 5, c4 = (flat & 31) * 4;
            float4 v = *(const float4*)(Vh + (long)(j0 + j) * HD + c4);
            VT[c4 + 0][j] = (_Float16)v.x;
            VT[c4 + 1][j] = (_Float16)v.y;
            VT[c4 + 2][j] = (_Float16)v.z;
            VT[c4 + 3][j] = (_Float16)v.w;
        }
        __syncthreads();
#pragma unroll
        for (int ks = 0; ks < 2; ++ks) {
            half8_t a[2], bf[4];
#pragma unroll
            for (int i = 0; i < 2; ++i)
                a[i] = *(const half8_t*)&PT[wm + i * 16 + l16][ks * 32 + quad * 8];
#pragma unroll
            for (int i = 0; i < 4; ++i)
                bf[i] = *(const half8_t*)&VT[wn + i * 16 + l16][ks * 32 + quad * 8];
#pragma unroll
            for (int mt = 0; mt < 2; ++mt)
#pragma unroll
                for (int nt = 0; nt < 4; ++nt)
                    acc[mt][nt] = __builtin_amdgcn_mfma_f32_16x16x32_f16(a[mt], bf[nt], acc[mt][nt], 0, 0, 0);
        }
        __syncthreads();
    }
    // write ctx [s][h*HD+hd]
#pragma unroll
    for (int mt = 0; mt < 2; ++mt)
#pragma unroll
        for (int nt = 0; nt < 4; ++nt)
#pragma unroll
            for (int r = 0; r < 4; ++r) {
                int s_ = m0 + wm + mt * 16 + quad * 4 + r;
                int hd = wn + nt * 16 + l16;
                ctx[(long)s_ * DMODEL + h * HD + hd] = acc[mt][nt][r];
            }
}

// ---------------------------------------------------------------------------
extern "C" void kernel_launch(void* const* d_in, const int* in_sizes, int n_in,
                              void* d_out, int out_size, void* d_ws, size_t ws_size,
                              hipStream_t stream)
{
    const float* hs = (const float*)d_in[0];
    // d_in[1] = attention_mask: structure known (causal), not needed
    const float* Wq = (const float*)d_in[2];
    const float* Wk = (const float*)d_in[3];
    const float* Wv = (const float*)d_in[4];
    const float* Wo = (const float*)d_in[5];
    float* out = (float*)d_out;

    char* w = (char*)d_ws;
    float* Qr  = (float*)w;  w += (long)HEADS * SEQ * HD * 4;   // 16MB
    float* Kr  = (float*)w;  w += (long)HEADS * SEQ * HD * 4;   // 16MB
    float* V   = (float*)w;  w += (long)HEADS * SEQ * HD * 4;   // 16MB
    float* ctx = (float*)w;  w += (long)SEQ * DMODEL * 4;       // 16MB
    float* mx1 = (float*)w;  w += (long)HEADS * SEQ * 4;
    float* rd1 = (float*)w;  w += (long)HEADS * SEQ * 4;
    float* mx2 = (float*)w;  w += (long)HEADS * SEQ * 4;
    float* rd2 = (float*)w;  w += (long)HEADS * SEQ * 4;
    uint32_t* mb = (uint32_t*)w; w += (long)HEADS * SEQ * 32 * 4; // 4MB
    float* S   = (float*)w;  w += (long)HEADS * SEQ * SEQ * 4;  // 134MB

    const float inv_sqrt_hd = 0.088388347648318447f; // 1/sqrt(128)

    dim3 gproj(DMODEL / 128, SEQ / 128, 1);
    // Q,K: fp32-precision split GEMM (mask decisions depend on them)
    gemm_f16<true, 1><<<gproj, 256, 0, stream>>>(hs, Wq, Qr, DMODEL, DMODEL, 0, 0, 0, 1.f);
    gemm_f16<true, 1><<<gproj, 256, 0, stream>>>(hs, Wk, Kr, DMODEL, DMODEL, 0, 0, 0, 1.f);
    // V: plain f16 MFMA
    gemm_f16<false, 1><<<gproj, 256, 0, stream>>>(hs, Wv, V, DMODEL, DMODEL, 0, 0, 0, 1.f);

    rope_kernel<<<(HEADS * SEQ * 64) / 256, 256, 0, stream>>>(Qr, Kr);

    // S = Q K^T / sqrt(hd), split precision, batched over heads
    dim3 gsc(SEQ / 128, SEQ / 128, HEADS);
    gemm_f16<true, 0><<<gsc, 256, 0, stream>>>(Qr, Kr, S, HD, SEQ,
        (long)SEQ * HD, (long)SEQ * HD, (long)SEQ * SEQ, inv_sqrt_hd);

    stats_kernel<<<HEADS * SEQ, 64, 0, stream>>>(S, mb, mx1, rd1, 1);
    scan_kernel<<<HEADS, 64, 0, stream>>>(S, mx1, rd1, mb);
    stats_kernel<<<HEADS * SEQ, 64, 0, stream>>>(S, mb, mx2, rd2, 2);
    pv_kernel<<<dim3(SEQ / 64, HEADS), 256, 0, stream>>>(S, V, mb, mx2, rd2, ctx);

    // out = ctx Wo^T
    gemm_f16<false, 0><<<gproj, 256, 0, stream>>>(ctx, Wo, out, DMODEL, DMODEL, 0, 0, 0, 1.f);
}